// Round 2
// baseline (450.795 us; speedup 1.0000x reference)
//
#include <hip/hip_runtime.h>
#include <hip/hip_bf16.h>

// Problem constants
#define B_   4
#define C_   2048
#define HH_  14
#define HW_  196      // 14*14
#define P_   784      // B_*HW_
#define K_   80
#define WD_  300
#define D_   1024

typedef float f32x4_t __attribute__((ext_vector_type(4)));

// ws layout (in floats)
#define XT_OFF    0                         // P_*C_   = 1605632
#define IPROJ_OFF (XT_OFF + P_*C_)          // P_*D_   = 802816
#define W2TS_OFF  (IPROJ_OFF + P_*D_)       // WD_*D_  = 307200
#define WPS_OFF   (W2TS_OFF + WD_*D_)       // K_*D_   = 81920
#define VD2_OFF   (WPS_OFF + K_*D_)         // D_      = 1024
#define S0_OFF    (VD2_OFF + D_)            // 4 (pad)
#define COEF_OFF  (S0_OFF + 4)              // P_*K_   = 62720
#define WS_FLOATS (COEF_OFF + P_*K_)

// ---------------- transpose img_feat (B,C,H,W) -> xt (P, C) ----------------
__global__ void k_transpose_x(const float* __restrict__ img, float* __restrict__ xt) {
  __shared__ float tile[32][33];
  int b  = blockIdx.z;
  int c0 = blockIdx.x * 32;
  int hw0 = blockIdx.y * 32;
  int tx = threadIdx.x % 32, ty = threadIdx.x / 32;   // 32x8
  #pragma unroll
  for (int i = 0; i < 4; i++) {
    int c = c0 + ty + i*8;
    int hw = hw0 + tx;
    float v = 0.f;
    if (hw < HW_) v = img[((size_t)b*C_ + c)*HW_ + hw];
    tile[ty + i*8][tx] = v;
  }
  __syncthreads();
  #pragma unroll
  for (int i = 0; i < 4; i++) {
    int hw = hw0 + ty + i*8;
    int c  = c0 + tx;
    if (hw < HW_) xt[((size_t)(b*HW_ + hw))*C_ + c] = tile[tx][ty + i*8];
  }
}

// ---------------- transpose+scale W2 (D,WD) -> w2ts (WD, D) * 2log2(e) -----
__global__ void k_transpose_w2(const float* __restrict__ W2, float* __restrict__ w2ts) {
  __shared__ float tile[32][33];
  int d0 = blockIdx.x * 32;
  int v0 = blockIdx.y * 32;
  int tx = threadIdx.x % 32, ty = threadIdx.x / 32;
  #pragma unroll
  for (int i = 0; i < 4; i++) {
    int d = d0 + ty + i*8, v = v0 + tx;
    float val = 0.f;
    if (v < WD_) val = W2[(size_t)d*WD_ + v];
    tile[ty + i*8][tx] = val;
  }
  __syncthreads();
  const float s = 2.8853900817779268f;  // 2*log2(e)
  #pragma unroll
  for (int i = 0; i < 4; i++) {
    int v = v0 + ty + i*8, d = d0 + tx;
    if (v < WD_) w2ts[(size_t)v*D_ + d] = tile[tx][ty + i*8] * s;
  }
}

// ---------------- wproj_s[k,d] = sum_v wf[k,v]*w2ts[v,d]  (already scaled) --
__global__ void k_wproj(const float* __restrict__ wf, const float* __restrict__ w2ts,
                        float* __restrict__ wps) {
  int k = blockIdx.x;
  int t = threadIdx.x;
  __shared__ float wrow[WD_];
  for (int i = t; i < WD_; i += 256) wrow[i] = wf[k*WD_ + i];
  __syncthreads();
  float4 acc = {0.f,0.f,0.f,0.f};
  const float4* w4 = (const float4*)w2ts;
  for (int v = 0; v < WD_; v++) {
    float s = wrow[v];
    float4 w = w4[(size_t)v*(D_/4) + t];
    acc.x = fmaf(s, w.x, acc.x); acc.y = fmaf(s, w.y, acc.y);
    acc.z = fmaf(s, w.z, acc.z); acc.w = fmaf(s, w.w, acc.w);
  }
  ((float4*)wps)[k*(D_/4) + t] = acc;
}

// ---------------- vd2[d] = -2 * sum_e W4[e]*W3[e,d] ------------------------
__global__ void k_vd2(const float* __restrict__ W3, const float* __restrict__ W4,
                      float* __restrict__ vd2) {
  int d = blockIdx.x*256 + threadIdx.x;
  __shared__ float w4s[D_];
  for (int i = threadIdx.x; i < D_; i += 256) w4s[i] = W4[i];
  __syncthreads();
  float acc = 0.f;
  for (int e = 0; e < D_; e++) acc = fmaf(w4s[e], W3[(size_t)e*D_ + d], acc);
  vd2[d] = -2.0f * acc;
}

// ---------------- S0 = b4 + dot(W4,b3) + sum_d v[d]  (v = -vd2/2) ----------
__global__ void k_s0(const float* __restrict__ b3, const float* __restrict__ W4,
                     const float* __restrict__ b4, const float* __restrict__ vd2,
                     float* __restrict__ s0) {
  int t = threadIdx.x;
  float a = 0.f;
  for (int i = t; i < D_; i += 256) a += W4[i]*b3[i] - 0.5f*vd2[i];
  __shared__ float red[256];
  red[t] = a; __syncthreads();
  for (int s = 128; s > 0; s >>= 1) { if (t < s) red[t] += red[t+s]; __syncthreads(); }
  if (t == 0) s0[0] = red[0] + b4[0];
}

// ---------------- iproj = xt(P,C) @ W1^T(C,D), fp32, splitK+atomics --------
#define BM 128
#define BN 128
#define BK 16
__launch_bounds__(256, 2)
__global__ void k_gemm(const float* __restrict__ xt, const float* __restrict__ W1,
                       float* __restrict__ iproj) {
  __shared__ float As[BK][BM+4];
  __shared__ float Bs[BK][BN+4];
  int m0 = blockIdx.y * BM;
  int n0 = blockIdx.x * BN;
  int kbase = blockIdx.z * 256;       // 8-way split over K=2048
  int t = threadIdx.x;
  int tx = t % 16, ty = t / 16;
  float acc[8][8] = {};
  for (int k0 = 0; k0 < 256; k0 += BK) {
    int q = t;
    #pragma unroll
    for (int rep = 0; rep < 2; rep++, q += 256) {
      int m = q >> 2, kq = (q & 3) * 4;
      int p = m0 + m;
      float4 v = {0.f,0.f,0.f,0.f};
      if (p < P_) v = *(const float4*)&xt[(size_t)p*C_ + kbase + k0 + kq];
      As[kq+0][m] = v.x; As[kq+1][m] = v.y; As[kq+2][m] = v.z; As[kq+3][m] = v.w;
    }
    q = t;
    #pragma unroll
    for (int rep = 0; rep < 2; rep++, q += 256) {
      int n = q >> 2, kq = (q & 3) * 4;
      float4 v = *(const float4*)&W1[(size_t)(n0 + n)*C_ + kbase + k0 + kq];
      Bs[kq+0][n] = v.x; Bs[kq+1][n] = v.y; Bs[kq+2][n] = v.z; Bs[kq+3][n] = v.w;
    }
    __syncthreads();
    #pragma unroll
    for (int kk = 0; kk < BK; kk++) {
      float a[8], b[8];
      *(float4*)&a[0] = *(const float4*)&As[kk][ty*8];
      *(float4*)&a[4] = *(const float4*)&As[kk][ty*8+4];
      *(float4*)&b[0] = *(const float4*)&Bs[kk][tx*8];
      *(float4*)&b[4] = *(const float4*)&Bs[kk][tx*8+4];
      #pragma unroll
      for (int i = 0; i < 8; i++)
        #pragma unroll
        for (int j = 0; j < 8; j++)
          acc[i][j] = fmaf(a[i], b[j], acc[i][j]);
    }
    __syncthreads();
  }
  #pragma unroll
  for (int i = 0; i < 8; i++) {
    int p = m0 + ty*8 + i;
    if (p < P_) {
      #pragma unroll
      for (int j = 0; j < 8; j++)
        atomicAdd(&iproj[(size_t)p*D_ + n0 + tx*8 + j], acc[i][j]);
    }
  }
}

// ---------------- coef[p,k] = S0 + sum_d vd2[d] * rcp(exp2(ip*wps)+1) ------
__launch_bounds__(320)
__global__ void k_coef(const float* __restrict__ iproj, const float* __restrict__ wps,
                       const float* __restrict__ vd2, const float* __restrict__ s0,
                       float* __restrict__ coef) {
  __shared__ float ipd[4][D_+8];
  __shared__ float v2s[D_];
  int p0 = blockIdx.x * 4;
  int t = threadIdx.x;
  for (int i = t; i < 4*D_; i += 320) {
    int pl = i >> 10, d = i & (D_-1);
    ipd[pl][d] = iproj[(size_t)(p0 + pl)*D_ + d];
  }
  for (int i = t; i < D_; i += 320) v2s[i] = vd2[i];
  __syncthreads();
  int k = t >> 2, pl = t & 3;            // lanes: 16 k-groups x 4 p each
  const float4* wv  = (const float4*)&wps[(size_t)k*D_];
  const float4* ip4 = (const float4*)&ipd[pl][0];
  const float4* v24 = (const float4*)&v2s[0];
  float acc = 0.f;
  for (int q = 0; q < D_/4; q++) {
    float4 w  = wv[q];
    float4 ip = ip4[q];
    float4 v2 = v24[q];
    float r0 = __builtin_amdgcn_rcpf(__builtin_amdgcn_exp2f(ip.x*w.x) + 1.0f);
    float r1 = __builtin_amdgcn_rcpf(__builtin_amdgcn_exp2f(ip.y*w.y) + 1.0f);
    float r2 = __builtin_amdgcn_rcpf(__builtin_amdgcn_exp2f(ip.z*w.z) + 1.0f);
    float r3 = __builtin_amdgcn_rcpf(__builtin_amdgcn_exp2f(ip.w*w.w) + 1.0f);
    acc = fmaf(v2.x, r0, acc);
    acc = fmaf(v2.y, r1, acc);
    acc = fmaf(v2.z, r2, acc);
    acc = fmaf(v2.w, r3, acc);
  }
  coef[(size_t)(p0 + pl)*K_ + k] = acc + s0[0];
}

// ---------------- softmax over HW per (b,k); sm in (B,H,W,K) layout --------
__global__ void k_softmax(const float* __restrict__ coef, float* __restrict__ sm) {
  int bk = blockIdx.x; int b = bk / K_, k = bk % K_;
  int t = threadIdx.x;                  // 64 threads = 1 wave
  float v[4]; float mx = -1e30f;
  #pragma unroll
  for (int i = 0; i < 4; i++) {
    int hw = t + i*64;
    v[i] = (hw < HW_) ? coef[(size_t)(b*HW_ + hw)*K_ + k] : -1e30f;
    mx = fmaxf(mx, v[i]);
  }
  #pragma unroll
  for (int off = 32; off > 0; off >>= 1) mx = fmaxf(mx, __shfl_xor(mx, off));
  float e[4]; float sum = 0.f;
  #pragma unroll
  for (int i = 0; i < 4; i++) {
    int hw = t + i*64;
    e[i] = (hw < HW_) ? __builtin_amdgcn_exp2f((v[i]-mx)*1.4426950408889634f) : 0.f;
    sum += e[i];
  }
  #pragma unroll
  for (int off = 32; off > 0; off >>= 1) sum += __shfl_xor(sum, off);
  float rs = 1.0f / sum;
  #pragma unroll
  for (int i = 0; i < 4; i++) {
    int hw = t + i*64;
    if (hw < HW_) sm[(size_t)(b*HW_ + hw)*K_ + k] = e[i]*rs;
  }
}

// ---------------- fwc = x*sm (write 514MB) + semantic reduce ---------------
__launch_bounds__(256)
__global__ void k_fwc(const float* __restrict__ xt, const float* __restrict__ sm,
                      float* __restrict__ fwc, float* __restrict__ semantic) {
  int c0 = blockIdx.x * 1024;
  int k  = blockIdx.y;
  int b  = blockIdx.z;
  int t  = threadIdx.x;
  __shared__ float srow[HW_];
  for (int i = t; i < HW_; i += 256) srow[i] = sm[(size_t)(b*HW_ + i)*K_ + k];
  __syncthreads();
  float4 acc = {0.f,0.f,0.f,0.f};
  for (int hw = 0; hw < HW_; hw++) {
    size_t p = (size_t)b*HW_ + hw;
    float4 x = *(const float4*)&xt[p*C_ + c0 + t*4];
    float s = srow[hw];
    f32x4_t w = {x.x*s, x.y*s, x.z*s, x.w*s};
    __builtin_nontemporal_store(w, (f32x4_t*)&fwc[(p*K_ + k)*C_ + c0 + t*4]);
    acc.x += w.x; acc.y += w.y; acc.z += w.z; acc.w += w.w;
  }
  *(float4*)&semantic[((size_t)(b*K_ + k))*C_ + c0 + t*4] = acc;
}

extern "C" void kernel_launch(void* const* d_in, const int* in_sizes, int n_in,
                              void* d_out, int out_size, void* d_ws, size_t ws_size,
                              hipStream_t stream) {
  const float* img  = (const float*)d_in[0];
  const float* wf   = (const float*)d_in[1];
  const float* W1   = (const float*)d_in[2];
  const float* W2   = (const float*)d_in[3];
  const float* W3   = (const float*)d_in[4];
  const float* b3   = (const float*)d_in[5];
  const float* W4   = (const float*)d_in[6];
  const float* b4   = (const float*)d_in[7];

  float* out = (float*)d_out;
  float* semantic = out;                                    // B*K*C
  float* fwc      = out + (size_t)B_*K_*C_;                 // B*HW*K*C
  float* sm       = fwc + (size_t)P_*K_*C_;                 // B*HW*K

  float* ws    = (float*)d_ws;
  float* xt    = ws + XT_OFF;
  float* iproj = ws + IPROJ_OFF;
  float* w2ts  = ws + W2TS_OFF;
  float* wps   = ws + WPS_OFF;
  float* vd2   = ws + VD2_OFF;
  float* s0    = ws + S0_OFF;
  float* coef  = ws + COEF_OFF;

  (void)hipMemsetAsync(iproj, 0, (size_t)P_*D_*sizeof(float), stream);

  k_transpose_x<<<dim3(C_/32, 7, B_), 256, 0, stream>>>(img, xt);
  k_transpose_w2<<<dim3(D_/32, 10), 256, 0, stream>>>(W2, w2ts);
  k_wproj<<<K_, 256, 0, stream>>>(wf, w2ts, wps);
  k_vd2<<<D_/256, 256, 0, stream>>>(W3, W4, vd2);
  k_s0<<<1, 256, 0, stream>>>(b3, W4, b4, vd2, s0);
  k_gemm<<<dim3(D_/BN, (P_ + BM - 1)/BM, 8), 256, 0, stream>>>(xt, W1, iproj);
  k_coef<<<P_/4, 320, 0, stream>>>(iproj, wps, vd2, s0, coef);
  k_softmax<<<B_*K_, 64, 0, stream>>>(coef, sm);
  k_fwc<<<dim3(C_/1024, K_, B_), 256, 0, stream>>>(xt, sm, fwc, semantic);
}

// Round 3
// 256.882 us; speedup vs baseline: 1.7549x; 1.7549x over previous
//
#include <hip/hip_runtime.h>
#include <hip/hip_bf16.h>

// Problem constants
#define B_   4
#define C_   2048
#define HH_  14
#define HW_  196      // 14*14
#define P_   784      // B_*HW_
#define PPAD_ 832     // 13*64 (gemm M padding)
#define K_   80
#define WD_  300
#define D_   1024

typedef float f32x4_t __attribute__((ext_vector_type(4)));
typedef short s16x8  __attribute__((ext_vector_type(8)));
typedef float f32x4a __attribute__((ext_vector_type(4)));
typedef unsigned short u16;
typedef u16 u16x4 __attribute__((ext_vector_type(4)));

// ws layout (in float units)
#define XT_OFF    0                          // P_*C_        = 1605632
#define XTB_OFF   (XT_OFF + P_*C_)           // PPAD_*C_ u16 = 851968 f
#define W1B_OFF   (XTB_OFF + (PPAD_*C_)/2)   // D_*C_ u16    = 1048576 f
#define IPROJ_OFF (W1B_OFF + (D_*C_)/2)      // P_*D_        = 802816
#define W2TS_OFF  (IPROJ_OFF + P_*D_)        // WD_*D_       = 307200
#define WPS_OFF   (W2TS_OFF + WD_*D_)        // K_*D_        = 81920
#define VD2_OFF   (WPS_OFF + K_*D_)          // D_
#define S0_OFF    (VD2_OFF + D_)             // 4
#define COEF_OFF  (S0_OFF + 4)               // P_*K_

static __device__ __forceinline__ u16 f2bf(float x) {
  __hip_bfloat16 h = __float2bfloat16(x);
  return *(u16*)&h;
}

// ---------------- transpose img_feat (B,C,H,W) -> xt (P,C) fp32 + xtb bf16 --
__global__ void k_transpose_x(const float* __restrict__ img, float* __restrict__ xt,
                              u16* __restrict__ xtb) {
  __shared__ float tile[32][33];
  int b  = blockIdx.z;
  int c0 = blockIdx.x * 32;
  int hw0 = blockIdx.y * 32;
  int tx = threadIdx.x % 32, ty = threadIdx.x / 32;   // 32x8
  #pragma unroll
  for (int i = 0; i < 4; i++) {
    int c = c0 + ty + i*8;
    int hw = hw0 + tx;
    float v = 0.f;
    if (hw < HW_) v = img[((size_t)b*C_ + c)*HW_ + hw];
    tile[ty + i*8][tx] = v;
  }
  __syncthreads();
  #pragma unroll
  for (int i = 0; i < 4; i++) {
    int hw = hw0 + ty + i*8;
    int c  = c0 + tx;
    if (hw < HW_) {
      float v = tile[tx][ty + i*8];
      size_t idx = ((size_t)(b*HW_ + hw))*C_ + c;
      xt[idx] = v;
      xtb[idx] = f2bf(v);
    }
  }
}

// ---------------- W1 (D,C) fp32 -> bf16 ------------------------------------
__global__ void k_w1bf16(const float* __restrict__ W1, u16* __restrict__ w1b) {
  int i = blockIdx.x*256 + threadIdx.x;     // i < D_*C_/4
  f32x4_t v = *(const f32x4_t*)&W1[(size_t)i*4];
  u16x4 o = { f2bf(v.x), f2bf(v.y), f2bf(v.z), f2bf(v.w) };
  *(u16x4*)&w1b[(size_t)i*4] = o;
}

// ---------------- transpose+scale W2 (D,WD) -> w2ts (WD,D) * 2log2(e) ------
__global__ void k_transpose_w2(const float* __restrict__ W2, float* __restrict__ w2ts) {
  __shared__ float tile[32][33];
  int d0 = blockIdx.x * 32;
  int v0 = blockIdx.y * 32;
  int tx = threadIdx.x % 32, ty = threadIdx.x / 32;
  #pragma unroll
  for (int i = 0; i < 4; i++) {
    int d = d0 + ty + i*8, v = v0 + tx;
    float val = 0.f;
    if (v < WD_) val = W2[(size_t)d*WD_ + v];
    tile[ty + i*8][tx] = val;
  }
  __syncthreads();
  const float s = 2.8853900817779268f;  // 2*log2(e)
  #pragma unroll
  for (int i = 0; i < 4; i++) {
    int v = v0 + ty + i*8, d = d0 + tx;
    if (v < WD_) w2ts[(size_t)v*D_ + d] = tile[tx][ty + i*8] * s;
  }
}

// ---------------- wproj_s[k,d] = sum_v wf[k,v]*w2ts[v,d]  (already scaled) --
__global__ void k_wproj(const float* __restrict__ wf, const float* __restrict__ w2ts,
                        float* __restrict__ wps) {
  int k = blockIdx.x;
  int t = threadIdx.x;
  __shared__ float wrow[WD_];
  for (int i = t; i < WD_; i += 256) wrow[i] = wf[k*WD_ + i];
  __syncthreads();
  float4 acc = {0.f,0.f,0.f,0.f};
  const float4* w4 = (const float4*)w2ts;
  for (int v = 0; v < WD_; v++) {
    float s = wrow[v];
    float4 w = w4[(size_t)v*(D_/4) + t];
    acc.x = fmaf(s, w.x, acc.x); acc.y = fmaf(s, w.y, acc.y);
    acc.z = fmaf(s, w.z, acc.z); acc.w = fmaf(s, w.w, acc.w);
  }
  ((float4*)wps)[k*(D_/4) + t] = acc;
}

// ---------------- vd2[d] = -2 * sum_e W4[e]*W3[e,d] ------------------------
__global__ void k_vd2(const float* __restrict__ W3, const float* __restrict__ W4,
                      float* __restrict__ vd2) {
  int d = blockIdx.x*256 + threadIdx.x;
  __shared__ float w4s[D_];
  for (int i = threadIdx.x; i < D_; i += 256) w4s[i] = W4[i];
  __syncthreads();
  float acc = 0.f;
  for (int e = 0; e < D_; e++) acc = fmaf(w4s[e], W3[(size_t)e*D_ + d], acc);
  vd2[d] = -2.0f * acc;
}

// ---------------- S0 = b4 + dot(W4,b3) + sum_d v[d]  (v = -vd2/2) ----------
__global__ void k_s0(const float* __restrict__ b3, const float* __restrict__ W4,
                     const float* __restrict__ b4, const float* __restrict__ vd2,
                     float* __restrict__ s0) {
  int t = threadIdx.x;
  float a = 0.f;
  for (int i = t; i < D_; i += 256) a += W4[i]*b3[i] - 0.5f*vd2[i];
  __shared__ float red[256];
  red[t] = a; __syncthreads();
  for (int s = 128; s > 0; s >>= 1) { if (t < s) red[t] += red[t+s]; __syncthreads(); }
  if (t == 0) s0[0] = red[0] + b4[0];
}

// ---------------- iproj = xtb(P,C) @ w1b^T(C,D), bf16 MFMA ----------------
// 64x64 tile, 4 waves (2x2), each wave 32x32 via 2x2 16x16x32 frags.
// LDS staged via global_load_lds width 16 with chunk-XOR swizzle
// (slot j ^ ((r>>1)&3)) -> ds_read_b128 is free-2-way conflict.
__launch_bounds__(256)
__global__ void k_gemm_mfma(const u16* __restrict__ xtb, const u16* __restrict__ w1b,
                            float* __restrict__ iproj) {
  __shared__ u16 As[64*32];
  __shared__ u16 Bs[64*32];
  const int t = threadIdx.x;
  const int m0 = blockIdx.y * 64, n0 = blockIdx.x * 64;
  const int wid = t >> 6, lane = t & 63;
  const int wm = wid >> 1, wn = wid & 1;
  // staging: thread i -> lds slot i (byte 16*i) <- global chunk (r=i>>2, j=(i&3)^((r>>1)&3))
  const int r = t >> 2, js = t & 3;
  const int j = js ^ ((r >> 1) & 3);
  const u16* gA = &xtb[(size_t)(m0 + r) * C_ + j * 8];
  const u16* gB = &w1b[(size_t)(n0 + r) * C_ + j * 8];
  u16* lA = &As[wid * 512];
  u16* lB = &Bs[wid * 512];
  const int jr = lane >> 4, lm = lane & 15;
  int raA[2], raB[2];
  #pragma unroll
  for (int mi = 0; mi < 2; mi++) {
    int ra = wm*32 + mi*16 + lm;
    raA[mi] = ra*32 + (jr ^ ((ra>>1)&3))*8;
    int rb = wn*32 + mi*16 + lm;
    raB[mi] = rb*32 + (jr ^ ((rb>>1)&3))*8;
  }
  f32x4a acc[2][2] = {};
  for (int k0 = 0; k0 < C_; k0 += 32) {
    __builtin_amdgcn_global_load_lds((const __attribute__((address_space(1))) void*)(gA + k0),
                                     (__attribute__((address_space(3))) void*)lA, 16, 0, 0);
    __builtin_amdgcn_global_load_lds((const __attribute__((address_space(1))) void*)(gB + k0),
                                     (__attribute__((address_space(3))) void*)lB, 16, 0, 0);
    __syncthreads();
    s16x8 a0 = *(const s16x8*)&As[raA[0]];
    s16x8 a1 = *(const s16x8*)&As[raA[1]];
    s16x8 b0 = *(const s16x8*)&Bs[raB[0]];
    s16x8 b1 = *(const s16x8*)&Bs[raB[1]];
    acc[0][0] = __builtin_amdgcn_mfma_f32_16x16x32_bf16(a0, b0, acc[0][0], 0, 0, 0);
    acc[0][1] = __builtin_amdgcn_mfma_f32_16x16x32_bf16(a0, b1, acc[0][1], 0, 0, 0);
    acc[1][0] = __builtin_amdgcn_mfma_f32_16x16x32_bf16(a1, b0, acc[1][0], 0, 0, 0);
    acc[1][1] = __builtin_amdgcn_mfma_f32_16x16x32_bf16(a1, b1, acc[1][1], 0, 0, 0);
    __syncthreads();
  }
  #pragma unroll
  for (int mi = 0; mi < 2; mi++)
    #pragma unroll
    for (int ni = 0; ni < 2; ni++)
      #pragma unroll
      for (int q = 0; q < 4; q++) {
        int prow = m0 + wm*32 + mi*16 + (lane>>4)*4 + q;
        int ncol = n0 + wn*32 + ni*16 + lm;
        if (prow < P_) iproj[(size_t)prow*D_ + ncol] = acc[mi][ni][q];
      }
}

// ---------------- coef[p,k] = S0 + sum_d vd2[d] * rcp(exp2(ip*wps)+1) ------
// block: 2 p-rows x 80 k x 2 d-halves = 320 threads, grid 392
__launch_bounds__(320)
__global__ void k_coef(const float* __restrict__ iproj, const float* __restrict__ wps,
                       const float* __restrict__ vd2, const float* __restrict__ s0,
                       float* __restrict__ coef) {
  __shared__ float ipd[2][D_];
  __shared__ float v2s[D_];
  __shared__ float pr[320];
  const int p0 = blockIdx.x * 2;
  const int t = threadIdx.x;
  for (int i = t; i < 2*D_; i += 320)
    ipd[i >> 10][i & (D_-1)] = iproj[(size_t)(p0 + (i >> 10))*D_ + (i & (D_-1))];
  for (int i = t; i < D_; i += 320) v2s[i] = vd2[i];
  __syncthreads();
  const int k = t >> 2, pl = t & 1, dh = (t >> 1) & 1;
  const float4* wv  = (const float4*)&wps[(size_t)k*D_ + dh*512];
  const float4* ip4 = (const float4*)&ipd[pl][dh*512];
  const float4* v24 = (const float4*)&v2s[dh*512];
  float acc = 0.f;
  for (int q = 0; q < 128; q++) {
    float4 w  = wv[q];
    float4 ip = ip4[q];
    float4 v2 = v24[q];
    float r0 = __builtin_amdgcn_rcpf(__builtin_amdgcn_exp2f(ip.x*w.x) + 1.0f);
    float r1 = __builtin_amdgcn_rcpf(__builtin_amdgcn_exp2f(ip.y*w.y) + 1.0f);
    float r2 = __builtin_amdgcn_rcpf(__builtin_amdgcn_exp2f(ip.z*w.z) + 1.0f);
    float r3 = __builtin_amdgcn_rcpf(__builtin_amdgcn_exp2f(ip.w*w.w) + 1.0f);
    acc = fmaf(v2.x, r0, acc);
    acc = fmaf(v2.y, r1, acc);
    acc = fmaf(v2.z, r2, acc);
    acc = fmaf(v2.w, r3, acc);
  }
  pr[t] = acc;
  __syncthreads();
  if (dh == 0) coef[(size_t)(p0 + pl)*K_ + k] = pr[t] + pr[t ^ 2] + s0[0];
}

// ---------------- softmax over HW per (b,k); sm in (B,H,W,K) layout --------
__global__ void k_softmax(const float* __restrict__ coef, float* __restrict__ sm) {
  int bk = blockIdx.x; int b = bk / K_, k = bk % K_;
  int t = threadIdx.x;                  // 64 threads = 1 wave
  float v[4]; float mx = -1e30f;
  #pragma unroll
  for (int i = 0; i < 4; i++) {
    int hw = t + i*64;
    v[i] = (hw < HW_) ? coef[(size_t)(b*HW_ + hw)*K_ + k] : -1e30f;
    mx = fmaxf(mx, v[i]);
  }
  #pragma unroll
  for (int off = 32; off > 0; off >>= 1) mx = fmaxf(mx, __shfl_xor(mx, off));
  float e[4]; float sum = 0.f;
  #pragma unroll
  for (int i = 0; i < 4; i++) {
    int hw = t + i*64;
    e[i] = (hw < HW_) ? __builtin_amdgcn_exp2f((v[i]-mx)*1.4426950408889634f) : 0.f;
    sum += e[i];
  }
  #pragma unroll
  for (int off = 32; off > 0; off >>= 1) sum += __shfl_xor(sum, off);
  float rs = 1.0f / sum;
  #pragma unroll
  for (int i = 0; i < 4; i++) {
    int hw = t + i*64;
    if (hw < HW_) sm[(size_t)(b*HW_ + hw)*K_ + k] = e[i]*rs;
  }
}

// ---------------- fwc write: block per (c-chunk, p); x read once -----------
__launch_bounds__(256)
__global__ void k_fwc_write(const float* __restrict__ xt, const float* __restrict__ sm,
                            float* __restrict__ fwc) {
  const int c0 = blockIdx.x * 1024;
  const int p  = blockIdx.y;            // 0..783
  const int t  = threadIdx.x;
  __shared__ float srow[K_];
  if (t < K_) srow[t] = sm[(size_t)p*K_ + t];
  __syncthreads();
  f32x4_t xv = *(const f32x4_t*)&xt[(size_t)p*C_ + c0 + t*4];
  float* base = &fwc[(size_t)p*K_*C_ + c0 + t*4];
  #pragma unroll 4
  for (int k = 0; k < K_; k++) {
    float s = srow[k];
    f32x4_t w = xv * s;
    __builtin_nontemporal_store(w, (f32x4_t*)(base + (size_t)k*C_));
  }
}

// ---------------- semantic[b,k,c] = sum_hw x[p,c]*sm[p,k] ------------------
// block: (b, c-chunk of 64); 4 waves split hw; LDS reduce. Deterministic.
__launch_bounds__(256)
__global__ void k_semantic(const float* __restrict__ xt, const float* __restrict__ sm,
                           float* __restrict__ semantic) {
  __shared__ float buf[256*K_];         // 80 KB; first holds sm tile (15680), then partials
  const int b = blockIdx.x;
  const int c0 = blockIdx.y * 64;
  const int t = threadIdx.x;
  const int w = t >> 6, ln = t & 63;
  for (int i = t; i < HW_*K_; i += 256) buf[i] = sm[(size_t)b*HW_*K_ + i];
  __syncthreads();
  float acc[K_];
  #pragma unroll
  for (int k = 0; k < K_; k++) acc[k] = 0.f;
  for (int hw = w; hw < HW_; hw += 4) {
    float xv = xt[(size_t)(b*HW_ + hw)*C_ + c0 + ln];
    #pragma unroll
    for (int k4 = 0; k4 < K_/4; k4++) {
      f32x4_t sv = *(const f32x4_t*)&buf[hw*K_ + k4*4];
      acc[k4*4+0] = fmaf(xv, sv.x, acc[k4*4+0]);
      acc[k4*4+1] = fmaf(xv, sv.y, acc[k4*4+1]);
      acc[k4*4+2] = fmaf(xv, sv.z, acc[k4*4+2]);
      acc[k4*4+3] = fmaf(xv, sv.w, acc[k4*4+3]);
    }
  }
  __syncthreads();
  #pragma unroll
  for (int k = 0; k < K_; k++) buf[t*K_ + k] = acc[k];
  __syncthreads();
  for (int kk = 0; kk < K_/4; kk++) {
    int k = w*(K_/4) + kk;
    float s = buf[(0*64+ln)*K_ + k] + buf[(1*64+ln)*K_ + k]
            + buf[(2*64+ln)*K_ + k] + buf[(3*64+ln)*K_ + k];
    semantic[((size_t)(b*K_ + k))*C_ + c0 + ln] = s;
  }
}

extern "C" void kernel_launch(void* const* d_in, const int* in_sizes, int n_in,
                              void* d_out, int out_size, void* d_ws, size_t ws_size,
                              hipStream_t stream) {
  const float* img  = (const float*)d_in[0];
  const float* wf   = (const float*)d_in[1];
  const float* W1   = (const float*)d_in[2];
  const float* W2   = (const float*)d_in[3];
  const float* W3   = (const float*)d_in[4];
  const float* b3   = (const float*)d_in[5];
  const float* W4   = (const float*)d_in[6];
  const float* b4   = (const float*)d_in[7];

  float* out = (float*)d_out;
  float* semantic = out;                                    // B*K*C
  float* fwc      = out + (size_t)B_*K_*C_;                 // B*HW*K*C
  float* sm       = fwc + (size_t)P_*K_*C_;                 // B*HW*K

  float* ws    = (float*)d_ws;
  float* xt    = ws + XT_OFF;
  u16*   xtb   = (u16*)(ws + XTB_OFF);
  u16*   w1b   = (u16*)(ws + W1B_OFF);
  float* iproj = ws + IPROJ_OFF;
  float* w2ts  = ws + W2TS_OFF;
  float* wps   = ws + WPS_OFF;
  float* vd2   = ws + VD2_OFF;
  float* s0    = ws + S0_OFF;
  float* coef  = ws + COEF_OFF;

  // zero gemm M-pad rows (784..831) of xtb
  (void)hipMemsetAsync(xtb + (size_t)P_*C_, 0, (size_t)(PPAD_-P_)*C_*sizeof(u16), stream);

  k_w1bf16<<<D_*C_/4/256, 256, 0, stream>>>(W1, w1b);
  k_transpose_x<<<dim3(C_/32, 7, B_), 256, 0, stream>>>(img, xt, xtb);
  k_transpose_w2<<<dim3(D_/32, 10), 256, 0, stream>>>(W2, w2ts);
  k_wproj<<<K_, 256, 0, stream>>>(wf, w2ts, wps);
  k_vd2<<<D_/256, 256, 0, stream>>>(W3, W4, vd2);
  k_s0<<<1, 256, 0, stream>>>(b3, W4, b4, vd2, s0);
  k_gemm_mfma<<<dim3(D_/64, PPAD_/64), 256, 0, stream>>>(xtb, w1b, iproj);
  k_coef<<<P_/2, 320, 0, stream>>>(iproj, wps, vd2, s0, coef);
  k_softmax<<<B_*K_, 64, 0, stream>>>(coef, sm);
  k_fwc_write<<<dim3(C_/1024, P_), 256, 0, stream>>>(xt, sm, fwc);
  k_semantic<<<dim3(B_, C_/64), 256, 0, stream>>>(xt, sm, semantic);
}

// Round 4
// 211.074 us; speedup vs baseline: 2.1357x; 1.2170x over previous
//
#include <hip/hip_runtime.h>
#include <hip/hip_bf16.h>

// Problem constants
#define B_   4
#define C_   2048
#define HH_  14
#define HW_  196      // 14*14
#define P_   784      // B_*HW_
#define PPAD_ 832     // 13*64 (gemm M padding)
#define K_   80
#define WD_  300
#define D_   1024

typedef float f32x4_t __attribute__((ext_vector_type(4)));
typedef short s16x8  __attribute__((ext_vector_type(8)));
typedef float f32x4a __attribute__((ext_vector_type(4)));
typedef unsigned short u16;
typedef u16 u16x4 __attribute__((ext_vector_type(4)));
typedef u16 u16x8 __attribute__((ext_vector_type(8)));

// ws layout (in float units)
#define XT_OFF    0                          // P_*C_        = 1605632
#define XTB_OFF   (XT_OFF + P_*C_)           // PPAD_*C_ u16 = 851968 f
#define W1B_OFF   (XTB_OFF + (PPAD_*C_)/2)   // D_*C_ u16    = 1048576 f
#define IPROJ_OFF (W1B_OFF + (D_*C_)/2)      // P_*D_        = 802816
#define W2TS_OFF  (IPROJ_OFF + P_*D_)        // WD_*D_       = 307200
#define WPS_OFF   (W2TS_OFF + WD_*D_)        // K_*D_        = 81920
#define VD2_OFF   (WPS_OFF + K_*D_)          // D_
#define VD2P_OFF  (VD2_OFF + D_)             // 32*D_ = 32768
#define S0_OFF    (VD2P_OFF + 32*D_)         // 4
#define COEF_OFF  (S0_OFF + 4)               // P_*K_

static __device__ __forceinline__ u16 f2bf(float x) {
  __hip_bfloat16 h = __float2bfloat16(x);
  return *(u16*)&h;
}

// ======== merged prep: roles by blockIdx.x =================================
// [0,2048)        : W1 fp32 -> bf16
// [2048,3840)     : transpose img -> xt fp32 + xtb bf16
// [3840,4160)     : transpose+scale W2 -> w2ts
// [4160,4288)     : vd2 partials: part[e/32][d] = sum_{32 e} W4[e]*W3[e,d]
// [4288,4296)     : zero xtb pad rows 784..831
#define PREP_BLOCKS 4296
__launch_bounds__(256)
__global__ void k_prep(const float* __restrict__ img, const float* __restrict__ W1,
                       const float* __restrict__ W2, const float* __restrict__ W3,
                       const float* __restrict__ W4,
                       float* __restrict__ xt, u16* __restrict__ xtb,
                       u16* __restrict__ w1b, float* __restrict__ w2ts,
                       float* __restrict__ vd2p) {
  __shared__ float tile[32][33];
  const int bid = blockIdx.x;
  const int t = threadIdx.x;
  if (bid < 2048) {                       // ---- W1 -> bf16
    int i = bid*256 + t;
    f32x4_t v = *(const f32x4_t*)&W1[(size_t)i*4];
    u16x4 o = { f2bf(v.x), f2bf(v.y), f2bf(v.z), f2bf(v.w) };
    *(u16x4*)&w1b[(size_t)i*4] = o;
  } else if (bid < 3840) {                // ---- transpose x
    int r = bid - 2048;
    int c0 = (r & 63) * 32;
    int hw0 = ((r >> 6) % 7) * 32;
    int b = r / 448;
    int tx = t & 31, ty = t >> 5;
    #pragma unroll
    for (int i = 0; i < 4; i++) {
      int c = c0 + ty + i*8, hw = hw0 + tx;
      float v = 0.f;
      if (hw < HW_) v = img[((size_t)b*C_ + c)*HW_ + hw];
      tile[ty + i*8][tx] = v;
    }
    __syncthreads();
    #pragma unroll
    for (int i = 0; i < 4; i++) {
      int hw = hw0 + ty + i*8, c = c0 + tx;
      if (hw < HW_) {
        float v = tile[tx][ty + i*8];
        size_t idx = ((size_t)(b*HW_ + hw))*C_ + c;
        xt[idx] = v;
        xtb[idx] = f2bf(v);
      }
    }
  } else if (bid < 4160) {                // ---- transpose+scale W2
    int r = bid - 3840;
    int d0 = (r & 31) * 32;
    int v0 = (r >> 5) * 32;
    int tx = t & 31, ty = t >> 5;
    #pragma unroll
    for (int i = 0; i < 4; i++) {
      int d = d0 + ty + i*8, v = v0 + tx;
      float val = 0.f;
      if (v < WD_) val = W2[(size_t)d*WD_ + v];
      tile[ty + i*8][tx] = val;
    }
    __syncthreads();
    const float s = 2.8853900817779268f;  // 2*log2(e)
    #pragma unroll
    for (int i = 0; i < 4; i++) {
      int v = v0 + ty + i*8, d = d0 + tx;
      if (v < WD_) w2ts[(size_t)v*D_ + d] = tile[tx][ty + i*8] * s;
    }
  } else if (bid < 4288) {                // ---- vd2 partials
    int r = bid - 4160;
    int d = (r & 3) * 256 + t;
    int e0 = (r >> 2) * 32;
    float acc = 0.f;
    #pragma unroll
    for (int q = 0; q < 32; q++)
      acc = fmaf(W4[e0 + q], W3[(size_t)(e0 + q)*D_ + d], acc);
    vd2p[(size_t)(r >> 2)*D_ + d] = acc;
  } else {                                // ---- zero xtb pad
    int r = bid - 4288;                   // 0..7
    u16x8 z = {0,0,0,0,0,0,0,0};
    // 48 rows * 2048 u16 = 98304 u16 = 12288 x u16x8; 8 blocks*256 thr -> 6 each
    #pragma unroll
    for (int i = 0; i < 6; i++) {
      size_t o = (size_t)P_*C_ + ((size_t)(r*256 + t)*6 + i)*8;
      *(u16x8*)&xtb[o] = z;
    }
  }
}

// ======== wproj_s[k,d] = sum_v wf[k,v]*w2ts[v,d]  (scale folded in) ========
__global__ void k_wproj(const float* __restrict__ wf, const float* __restrict__ w2ts,
                        float* __restrict__ wps) {
  int k = blockIdx.x;
  int t = threadIdx.x;
  __shared__ float wrow[WD_];
  for (int i = t; i < WD_; i += 256) wrow[i] = wf[k*WD_ + i];
  __syncthreads();
  float4 acc = {0.f,0.f,0.f,0.f};
  const float4* w4 = (const float4*)w2ts;
  for (int v = 0; v < WD_; v++) {
    float s = wrow[v];
    float4 w = w4[(size_t)v*(D_/4) + t];
    acc.x = fmaf(s, w.x, acc.x); acc.y = fmaf(s, w.y, acc.y);
    acc.z = fmaf(s, w.z, acc.z); acc.w = fmaf(s, w.w, acc.w);
  }
  ((float4*)wps)[k*(D_/4) + t] = acc;
}

// ======== vd2 finalize + S0 ================================================
__launch_bounds__(1024)
__global__ void k_vd2fs0(const float* __restrict__ W4, const float* __restrict__ b3,
                         const float* __restrict__ b4, const float* __restrict__ vd2p,
                         float* __restrict__ vd2, float* __restrict__ s0) {
  int d = threadIdx.x;                  // 1024 threads
  float s = 0.f;
  #pragma unroll
  for (int q = 0; q < 32; q++) s += vd2p[(size_t)q*D_ + d];
  vd2[d] = -2.0f * s;
  __shared__ float red[1024];
  red[d] = fmaf(W4[d], b3[d], s);
  __syncthreads();
  for (int st = 512; st > 0; st >>= 1) {
    if (d < st) red[d] += red[d + st];
    __syncthreads();
  }
  if (d == 0) s0[0] = red[0] + b4[0];
}

// ======== iproj = xtb(P,C) @ w1b^T(C,D), bf16 MFMA, BK=256 =================
// 64x64 tile, 4 waves (2x2), 16 global_load_lds in flight per K-tile.
// LDS slot swizzle: store chunk j at slot j^(row&7)  (inverse-swz source,
// swz read) -> ds_read_b128 is 2-way (free).
#define GK_ 256
__launch_bounds__(256, 2)
__global__ void k_gemm_mfma(const u16* __restrict__ xtb, const u16* __restrict__ w1b,
                            float* __restrict__ iproj) {
  __shared__ u16 As[64*GK_];            // 32KB
  __shared__ u16 Bs[64*GK_];            // 32KB
  const int t = threadIdx.x;
  const int m0 = blockIdx.y * 64, n0 = blockIdx.x * 64;
  const int wid = t >> 6, lane = t & 63;
  const int wm = wid >> 1, wn = wid & 1;
  const int lm = lane & 15, jr = lane >> 4;
  // staging geometry: chunk c=i*256+t -> lds byte c*16; source chunk j = slot^(row&7)
  int offA[8], offB[8];
  u16* ldsA[8]; u16* ldsB[8];
  #pragma unroll
  for (int i = 0; i < 8; i++) {
    int c = i*256 + t;
    int row = c >> 5, js = c & 31;
    int j = js ^ (row & 7);
    offA[i] = (m0 + row) * C_ + j*8;
    offB[i] = (n0 + row) * C_ + j*8;
    ldsA[i] = &As[c*8];
    ldsB[i] = &Bs[c*8];
  }
  f32x4a acc[2][2] = {};
  for (int k0 = 0; k0 < C_; k0 += GK_) {
    #pragma unroll
    for (int i = 0; i < 8; i++)
      __builtin_amdgcn_global_load_lds((const __attribute__((address_space(1))) void*)(xtb + offA[i] + k0),
                                       (__attribute__((address_space(3))) void*)ldsA[i], 16, 0, 0);
    #pragma unroll
    for (int i = 0; i < 8; i++)
      __builtin_amdgcn_global_load_lds((const __attribute__((address_space(1))) void*)(w1b + offB[i] + k0),
                                       (__attribute__((address_space(3))) void*)ldsB[i], 16, 0, 0);
    __syncthreads();
    #pragma unroll
    for (int kk = 0; kk < 8; kk++) {
      int jx = ((kk*4 + jr) ^ (lm & 7)) * 8;
      s16x8 a0 = *(const s16x8*)&As[(wm*32 + lm)*GK_ + jx];
      s16x8 a1 = *(const s16x8*)&As[(wm*32 + 16 + lm)*GK_ + jx];
      s16x8 b0 = *(const s16x8*)&Bs[(wn*32 + lm)*GK_ + jx];
      s16x8 b1 = *(const s16x8*)&Bs[(wn*32 + 16 + lm)*GK_ + jx];
      acc[0][0] = __builtin_amdgcn_mfma_f32_16x16x32_bf16(a0, b0, acc[0][0], 0, 0, 0);
      acc[0][1] = __builtin_amdgcn_mfma_f32_16x16x32_bf16(a0, b1, acc[0][1], 0, 0, 0);
      acc[1][0] = __builtin_amdgcn_mfma_f32_16x16x32_bf16(a1, b0, acc[1][0], 0, 0, 0);
      acc[1][1] = __builtin_amdgcn_mfma_f32_16x16x32_bf16(a1, b1, acc[1][1], 0, 0, 0);
    }
    __syncthreads();
  }
  #pragma unroll
  for (int mi = 0; mi < 2; mi++)
    #pragma unroll
    for (int ni = 0; ni < 2; ni++)
      #pragma unroll
      for (int q = 0; q < 4; q++) {
        int prow = m0 + wm*32 + mi*16 + (lane>>4)*4 + q;
        int ncol = n0 + wn*32 + ni*16 + lm;
        if (prow < P_) iproj[(size_t)prow*D_ + ncol] = acc[mi][ni][q];
      }
}

// ======== coef[p,k] = S0 + sum_d vd2[d] * rcp(exp2(ip*wps)+1) ==============
__launch_bounds__(320)
__global__ void k_coef(const float* __restrict__ iproj, const float* __restrict__ wps,
                       const float* __restrict__ vd2, const float* __restrict__ s0,
                       float* __restrict__ coef) {
  __shared__ float ipd[2][D_];
  __shared__ float v2s[D_];
  __shared__ float pr[320];
  const int p0 = blockIdx.x * 2;
  const int t = threadIdx.x;
  for (int i = t; i < 2*D_; i += 320)
    ipd[i >> 10][i & (D_-1)] = iproj[(size_t)(p0 + (i >> 10))*D_ + (i & (D_-1))];
  for (int i = t; i < D_; i += 320) v2s[i] = vd2[i];
  __syncthreads();
  const int k = t >> 2, pl = t & 1, dh = (t >> 1) & 1;
  const float4* wv  = (const float4*)&wps[(size_t)k*D_ + dh*512];
  const float4* ip4 = (const float4*)&ipd[pl][dh*512];
  const float4* v24 = (const float4*)&v2s[dh*512];
  float acc = 0.f;
  for (int q = 0; q < 128; q++) {
    float4 w  = wv[q];
    float4 ip = ip4[q];
    float4 v2 = v24[q];
    float r0 = __builtin_amdgcn_rcpf(__builtin_amdgcn_exp2f(ip.x*w.x) + 1.0f);
    float r1 = __builtin_amdgcn_rcpf(__builtin_amdgcn_exp2f(ip.y*w.y) + 1.0f);
    float r2 = __builtin_amdgcn_rcpf(__builtin_amdgcn_exp2f(ip.z*w.z) + 1.0f);
    float r3 = __builtin_amdgcn_rcpf(__builtin_amdgcn_exp2f(ip.w*w.w) + 1.0f);
    acc = fmaf(v2.x, r0, acc);
    acc = fmaf(v2.y, r1, acc);
    acc = fmaf(v2.z, r2, acc);
    acc = fmaf(v2.w, r3, acc);
  }
  pr[t] = acc;
  __syncthreads();
  if (dh == 0) coef[(size_t)(p0 + pl)*K_ + k] = pr[t] + pr[t ^ 2] + s0[0];
}

// ======== softmax over HW per (b,k) ========================================
__global__ void k_softmax(const float* __restrict__ coef, float* __restrict__ sm) {
  int bk = blockIdx.x; int b = bk / K_, k = bk % K_;
  int t = threadIdx.x;                  // 64 threads = 1 wave
  float v[4]; float mx = -1e30f;
  #pragma unroll
  for (int i = 0; i < 4; i++) {
    int hw = t + i*64;
    v[i] = (hw < HW_) ? coef[(size_t)(b*HW_ + hw)*K_ + k] : -1e30f;
    mx = fmaxf(mx, v[i]);
  }
  #pragma unroll
  for (int off = 32; off > 0; off >>= 1) mx = fmaxf(mx, __shfl_xor(mx, off));
  float e[4]; float sum = 0.f;
  #pragma unroll
  for (int i = 0; i < 4; i++) {
    int hw = t + i*64;
    e[i] = (hw < HW_) ? __builtin_amdgcn_exp2f((v[i]-mx)*1.4426950408889634f) : 0.f;
    sum += e[i];
  }
  #pragma unroll
  for (int off = 32; off > 0; off >>= 1) sum += __shfl_xor(sum, off);
  float rs = 1.0f / sum;
  #pragma unroll
  for (int i = 0; i < 4; i++) {
    int hw = t + i*64;
    if (hw < HW_) sm[(size_t)(b*HW_ + hw)*K_ + k] = e[i]*rs;
  }
}

// ======== fwc write: block per (c-chunk, p); x read once ===================
__launch_bounds__(256)
__global__ void k_fwc_write(const float* __restrict__ xt, const float* __restrict__ sm,
                            float* __restrict__ fwc) {
  const int c0 = blockIdx.x * 1024;
  const int p  = blockIdx.y;            // 0..783
  const int t  = threadIdx.x;
  __shared__ float srow[K_];
  if (t < K_) srow[t] = sm[(size_t)p*K_ + t];
  __syncthreads();
  f32x4_t xv = *(const f32x4_t*)&xt[(size_t)p*C_ + c0 + t*4];
  float* base = &fwc[(size_t)p*K_*C_ + c0 + t*4];
  #pragma unroll 4
  for (int k = 0; k < K_; k++) {
    float s = srow[k];
    f32x4_t w = xv * s;
    __builtin_nontemporal_store(w, (f32x4_t*)(base + (size_t)k*C_));
  }
}

// ======== semantic[b,k,c] = sum_hw x[p,c]*sm[p,k] ==========================
__launch_bounds__(256)
__global__ void k_semantic(const float* __restrict__ xt, const float* __restrict__ sm,
                           float* __restrict__ semantic) {
  __shared__ float buf[256*K_];         // 80 KB
  const int b = blockIdx.x;
  const int c0 = blockIdx.y * 64;
  const int t = threadIdx.x;
  const int w = t >> 6, ln = t & 63;
  for (int i = t; i < HW_*K_; i += 256) buf[i] = sm[(size_t)b*HW_*K_ + i];
  __syncthreads();
  float acc[K_];
  #pragma unroll
  for (int k = 0; k < K_; k++) acc[k] = 0.f;
  for (int hw = w; hw < HW_; hw += 4) {
    float xv = xt[(size_t)(b*HW_ + hw)*C_ + c0 + ln];
    #pragma unroll
    for (int k4 = 0; k4 < K_/4; k4++) {
      f32x4_t sv = *(const f32x4_t*)&buf[hw*K_ + k4*4];
      acc[k4*4+0] = fmaf(xv, sv.x, acc[k4*4+0]);
      acc[k4*4+1] = fmaf(xv, sv.y, acc[k4*4+1]);
      acc[k4*4+2] = fmaf(xv, sv.z, acc[k4*4+2]);
      acc[k4*4+3] = fmaf(xv, sv.w, acc[k4*4+3]);
    }
  }
  __syncthreads();
  #pragma unroll
  for (int k = 0; k < K_; k++) buf[t*K_ + k] = acc[k];
  __syncthreads();
  for (int kk = 0; kk < K_/4; kk++) {
    int k = w*(K_/4) + kk;
    float s = buf[(0*64+ln)*K_ + k] + buf[(1*64+ln)*K_ + k]
            + buf[(2*64+ln)*K_ + k] + buf[(3*64+ln)*K_ + k];
    semantic[((size_t)(b*K_ + k))*C_ + c0 + ln] = s;
  }
}

extern "C" void kernel_launch(void* const* d_in, const int* in_sizes, int n_in,
                              void* d_out, int out_size, void* d_ws, size_t ws_size,
                              hipStream_t stream) {
  const float* img  = (const float*)d_in[0];
  const float* wf   = (const float*)d_in[1];
  const float* W1   = (const float*)d_in[2];
  const float* W2   = (const float*)d_in[3];
  const float* W3   = (const float*)d_in[4];
  const float* b3   = (const float*)d_in[5];
  const float* W4   = (const float*)d_in[6];
  const float* b4   = (const float*)d_in[7];

  float* out = (float*)d_out;
  float* semantic = out;                                    // B*K*C
  float* fwc      = out + (size_t)B_*K_*C_;                 // B*HW*K*C
  float* sm       = fwc + (size_t)P_*K_*C_;                 // B*HW*K

  float* ws    = (float*)d_ws;
  float* xt    = ws + XT_OFF;
  u16*   xtb   = (u16*)(ws + XTB_OFF);
  u16*   w1b   = (u16*)(ws + W1B_OFF);
  float* iproj = ws + IPROJ_OFF;
  float* w2ts  = ws + W2TS_OFF;
  float* wps   = ws + WPS_OFF;
  float* vd2   = ws + VD2_OFF;
  float* vd2p  = ws + VD2P_OFF;
  float* s0    = ws + S0_OFF;
  float* coef  = ws + COEF_OFF;

  k_prep<<<PREP_BLOCKS, 256, 0, stream>>>(img, W1, W2, W3, W4, xt, xtb, w1b, w2ts, vd2p);
  k_wproj<<<K_, 256, 0, stream>>>(wf, w2ts, wps);
  k_vd2fs0<<<1, 1024, 0, stream>>>(W4, b3, b4, vd2p, vd2, s0);
  k_gemm_mfma<<<dim3(D_/64, PPAD_/64), 256, 0, stream>>>(xtb, w1b, iproj);
  k_coef<<<P_/2, 320, 0, stream>>>(iproj, wps, vd2, s0, coef);
  k_softmax<<<B_*K_, 64, 0, stream>>>(coef, sm);
  k_fwc_write<<<dim3(C_/1024, P_), 256, 0, stream>>>(xt, sm, fwc);
  k_semantic<<<dim3(B_, C_/64), 256, 0, stream>>>(xt, sm, semantic);
}